// Round 12
// baseline (362.552 us; speedup 1.0000x reference)
//
#include <hip/hip_runtime.h>
#include <hip/hip_bf16.h>

#define NTOT   65536
#define CDIM   128
#define NE     1048576
#define NGRAPH 64
#define NNODE  1024
#define NLAYER 4
#define SLOPE  0.01f
#define PAD    64

typedef __attribute__((ext_vector_type(8))) short short8;   // 8 bf16 (4 VGPRs) MFMA frag
typedef __attribute__((ext_vector_type(4))) float f32x4;    // MFMA accum frag
typedef __attribute__((ext_vector_type(8))) unsigned short ushort8v;
typedef unsigned int u32;
typedef unsigned short u16;

__device__ __forceinline__ float bf2f_lo(u32 v){ return __uint_as_float(v << 16); }
__device__ __forceinline__ float bf2f_hi(u32 v){ return __uint_as_float(v & 0xffff0000u); }
__device__ __forceinline__ u16 f2bf(float f){
    u32 u = __float_as_uint(f);
    u += 0x7fffu + ((u >> 16) & 1u);      // round-to-nearest-even
    return (u16)(u >> 16);
}
__device__ __forceinline__ float lk(float x){ return x >= 0.f ? x : SLOPE * x; }

// predicated accumulate: 1 cndmask + 8 fmac. Garbage rows are always finite
// (any u16 index is in-bounds of h, rows always fully initialized), so 0*val = 0.
__device__ __forceinline__ void accm(float* a, uint4 w, bool pr){
    float f = pr ? 1.f : 0.f;
    a[0] = fmaf(f, bf2f_lo(w.x), a[0]); a[1] = fmaf(f, bf2f_hi(w.x), a[1]);
    a[2] = fmaf(f, bf2f_lo(w.y), a[2]); a[3] = fmaf(f, bf2f_hi(w.y), a[3]);
    a[4] = fmaf(f, bf2f_lo(w.z), a[4]); a[5] = fmaf(f, bf2f_hi(w.z), a[5]);
    a[6] = fmaf(f, bf2f_lo(w.w), a[6]); a[7] = fmaf(f, bf2f_hi(w.w), a[7]);
}

// ---------------- cast x (f32) -> h (bf16) ----------------
__global__ void k_cast_x(const float* __restrict__ x, u16* __restrict__ h){
    int i = blockIdx.x * 256 + threadIdx.x;          // 8 elems per thread
    const float4* x4 = (const float4*)x;
    float4 a = x4[i * 2], b = x4[i * 2 + 1];
    u32 r0 = (u32)f2bf(a.x) | ((u32)f2bf(a.y) << 16);
    u32 r1 = (u32)f2bf(a.z) | ((u32)f2bf(a.w) << 16);
    u32 r2 = (u32)f2bf(b.x) | ((u32)f2bf(b.y) << 16);
    u32 r3 = (u32)f2bf(b.z) | ((u32)f2bf(b.w) << 16);
    ((uint4*)h)[i] = make_uint4(r0, r1, r2, r3);
}

// ------- convert + transpose weights: Wt[l][g][c][k] = (bf16) W_g[l][k][c] -------
__global__ void k_conv_w(const float* __restrict__ W1, const float* __restrict__ W2,
                         u16* __restrict__ Wt){
    int idx = blockIdx.x * 256 + threadIdx.x;        // L*2*128*128 = 131072
    int k = idx & 127;
    int c = (idx >> 7) & 127;
    int g = (idx >> 14) & 1;
    int l = idx >> 15;
    const float* W = g ? W2 : W1;
    Wt[idx] = f2bf(W[(l * 128 + k) * 128 + c]);
}

// ------- XCD-partitioned padded-CSR fill -------
__global__ void k_fillx(const int* __restrict__ src, const int* __restrict__ dst,
                        int* __restrict__ cnt, u16* __restrict__ csrp){
    int part = blockIdx.x & 7;
    int g    = blockIdx.x >> 3;                       // 0..511
    int e0   = g * 2048 + threadIdx.x * 8;
    int4 d0 = *(const int4*)(dst + e0);
    int4 d1 = *(const int4*)(dst + e0 + 4);
    int4 s0 = *(const int4*)(src + e0);
    int4 s1 = *(const int4*)(src + e0 + 4);
    int d, s, p;
    #define DO_EDGE(dd, ss) d = (dd); s = (ss); \
        if ((d >> 13) == part){ p = atomicAdd(&cnt[d], 1); if (p < PAD) csrp[d * PAD + p] = (u16)s; }
    DO_EDGE(d0.x, s0.x); DO_EDGE(d0.y, s0.y); DO_EDGE(d0.z, s0.z); DO_EDGE(d0.w, s0.w);
    DO_EDGE(d1.x, s1.x); DO_EDGE(d1.y, s1.y); DO_EDGE(d1.z, s1.z); DO_EDGE(d1.w, s1.w);
    #undef DO_EDGE
}

// 8-row gather into named register set (static indices, rule #20)
#define LD8(P, I) \
    P##0 = h4[(size_t)(I)[0] * 16 + l16c]; \
    P##1 = h4[(size_t)(I)[1] * 16 + l16c]; \
    P##2 = h4[(size_t)(I)[2] * 16 + l16c]; \
    P##3 = h4[(size_t)(I)[3] * 16 + l16c]; \
    P##4 = h4[(size_t)(I)[4] * 16 + l16c]; \
    P##5 = h4[(size_t)(I)[5] * 16 + l16c]; \
    P##6 = h4[(size_t)(I)[6] * 16 + l16c]; \
    P##7 = h4[(size_t)(I)[7] * 16 + l16c];

#define ACC8P(P, base) \
    accm(a0, P##0, (base) + 0 < e); accm(a1, P##1, (base) + 1 < e); \
    accm(a0, P##2, (base) + 2 < e); accm(a1, P##3, (base) + 3 < e); \
    accm(a0, P##4, (base) + 4 < e); accm(a1, P##5, (base) + 5 < e); \
    accm(a0, P##6, (base) + 6 < e); accm(a1, P##7, (base) + 7 < e);

// ------- fused layer at GATHER geometry: 16 nodes/block, 4096 blocks -------
// Phase 0: gather with explicit 3-deep ROW-load pipeline (chunks c+1 and c+2 in
//          flight while accumulating chunk c -> typical node (nch~2.6) fully
//          covered). Speculative chunks index-masked to row 0 (hot line).
// Phase 1/2: 4 waves; wave w computes cols [w*32, w*32+32) of both GEMMs.
__global__ __launch_bounds__(256) void k_layer16(const u16* __restrict__ h,
                                                 const int* __restrict__ cnt,
                                                 const u16* __restrict__ csrp,
                                                 const u16* __restrict__ Wt,
                                                 const float* __restrict__ b1,
                                                 const float* __restrict__ b2,
                                                 u16* __restrict__ hout,
                                                 const float* __restrict__ fc1_w,
                                                 const float* __restrict__ fc1_b,
                                                 float* __restrict__ y,
                                                 int layer, int act, int fuse_fc1){
    __shared__ __align__(16) u16 t_lds[16][136];      // agg result (A for GEMM1)
    __shared__ __align__(16) u16 u_lds[16][136];      // GEMM1 out (A for GEMM2)
    __shared__ float fcp[4][16];                      // FC1 per-wave partials
    int tid = threadIdx.x;
    int nb  = blockIdx.x;

    // ---- phase 0: gather ----
    {
        int row  = tid >> 4;
        int l16c = tid & 15;
        int n = nb * 16 + row;
        const uint4* h4 = (const uint4*)h;
        int e = min(cnt[n], PAD);
        const u16* rowp = csrp + (size_t)n * PAD;
        int nch = (e + 7) >> 3;

        float a0[8], a1[8];
        uint4 v = h4[(size_t)n * 16 + l16c];
        a0[0] = bf2f_lo(v.x); a0[1] = bf2f_hi(v.x);
        a0[2] = bf2f_lo(v.y); a0[3] = bf2f_hi(v.y);
        a0[4] = bf2f_lo(v.z); a0[5] = bf2f_hi(v.z);
        a0[6] = bf2f_lo(v.w); a0[7] = bf2f_hi(v.w);
        for (int f = 0; f < 8; ++f) a1[f] = 0.f;

        uint4 A0, A1, A2, A3, A4, A5, A6, A7;
        uint4 B0, B1, B2, B3, B4, B5, B6, B7;
        uint4 C0, C1, C2, C3, C4, C5, C6, C7;
        ushort8v zer = (ushort8v)0;

        // prime: chunks 0 and 1 in flight
        ushort8v iA = (nch > 0) ? *(const ushort8v*)(rowp) : zer;
        LD8(A, iA);
        ushort8v iB = (nch > 1) ? *(const ushort8v*)(rowp + 8) : zer;
        LD8(B, iB);

        int c = 0;
        while (c < nch){
            ushort8v iC = (c + 2 < nch) ? *(const ushort8v*)(rowp + (size_t)(c + 2) * 8) : zer;
            LD8(C, iC);
            ACC8P(A, c * 8);
            ++c;
            if (c >= nch) break;
            iA = (c + 2 < nch) ? *(const ushort8v*)(rowp + (size_t)(c + 2) * 8) : zer;
            LD8(A, iA);
            ACC8P(B, c * 8);
            ++c;
            if (c >= nch) break;
            iB = (c + 2 < nch) ? *(const ushort8v*)(rowp + (size_t)(c + 2) * 8) : zer;
            LD8(B, iB);
            ACC8P(C, c * 8);
            ++c;
        }

        u32 r0 = (u32)f2bf(a0[0] + a1[0]) | ((u32)f2bf(a0[1] + a1[1]) << 16);
        u32 r1 = (u32)f2bf(a0[2] + a1[2]) | ((u32)f2bf(a0[3] + a1[3]) << 16);
        u32 r2 = (u32)f2bf(a0[4] + a1[4]) | ((u32)f2bf(a0[5] + a1[5]) << 16);
        u32 r3 = (u32)f2bf(a0[6] + a1[6]) | ((u32)f2bf(a0[7] + a1[7]) << 16);
        *(uint4*)(&t_lds[row][l16c * 8]) = make_uint4(r0, r1, r2, r3);
    }
    __syncthreads();

    int wid = tid >> 6, lane = tid & 63;
    int l16 = lane & 15, kg = lane >> 4;
    const u16* Wt1 = Wt + (size_t)(layer * 2) * 16384;
    const u16* Wt2 = Wt1 + 16384;

    // ---- GEMM1: U[:, wid*32 .. +32) = T @ W1 slice ----
    f32x4 acc[2];
    acc[0] = (f32x4){0.f, 0.f, 0.f, 0.f};
    acc[1] = (f32x4){0.f, 0.f, 0.f, 0.f};
    for (int ks = 0; ks < 4; ++ks){
        int k0 = ks * 32 + kg * 8;
        short8 afrag = *(const short8*)(&t_lds[l16][k0]);
        for (int f = 0; f < 2; ++f){
            short8 bfrag = *(const short8*)(Wt1 + (size_t)(wid * 32 + f * 16 + l16) * 128 + k0);
            acc[f] = __builtin_amdgcn_mfma_f32_16x16x32_bf16(afrag, bfrag, acc[f], 0, 0, 0);
        }
    }
    for (int f = 0; f < 2; ++f){
        int col = wid * 32 + f * 16 + l16;
        float bv = b1[layer * 128 + col];
        for (int j = 0; j < 4; ++j)
            u_lds[kg * 4 + j][col] = f2bf(lk(acc[f][j] + bv));
    }
    __syncthreads();

    // ---- GEMM2: H[:, wid*32 .. +32) = U @ W2 slice ----
    f32x4 acc2[2];
    acc2[0] = (f32x4){0.f, 0.f, 0.f, 0.f};
    acc2[1] = (f32x4){0.f, 0.f, 0.f, 0.f};
    for (int ks = 0; ks < 4; ++ks){
        int k0 = ks * 32 + kg * 8;
        short8 afrag = *(const short8*)(&u_lds[l16][k0]);
        for (int f = 0; f < 2; ++f){
            short8 bfrag = *(const short8*)(Wt2 + (size_t)(wid * 32 + f * 16 + l16) * 128 + k0);
            acc2[f] = __builtin_amdgcn_mfma_f32_16x16x32_bf16(afrag, bfrag, acc2[f], 0, 0, 0);
        }
    }

    if (fuse_fc1){
        float part[4] = {0.f, 0.f, 0.f, 0.f};
        for (int f = 0; f < 2; ++f){
            int col = wid * 32 + f * 16 + l16;
            float bv = b2[layer * 128 + col];
            float wv = fc1_w[col];
            for (int j = 0; j < 4; ++j)
                part[j] += lk(acc2[f][j] + bv) * wv;
        }
        for (int off = 8; off; off >>= 1)
            for (int j = 0; j < 4; ++j)
                part[j] += __shfl_xor(part[j], off, 64);
        if (l16 == 0)
            for (int j = 0; j < 4; ++j)
                fcp[wid][kg * 4 + j] = part[j];
        __syncthreads();
        if (tid < 16)
            y[nb * 16 + tid] = fcp[0][tid] + fcp[1][tid] + fcp[2][tid] + fcp[3][tid] + fc1_b[0];
    } else {
        for (int f = 0; f < 2; ++f){
            int col = wid * 32 + f * 16 + l16;
            float bv = b2[layer * 128 + col];
            for (int j = 0; j < 4; ++j){
                float v = acc2[f][j] + bv;
                if (act) v = lk(v);
                hout[(size_t)(nb * 16 + kg * 4 + j) * 128 + col] = f2bf(v);
            }
        }
    }
}

// ---------------- FC2 + log_softmax ----------------
__global__ void k_fc2(const float* __restrict__ y, const float* __restrict__ fc2_w,
                      const float* __restrict__ fc2_b, float* __restrict__ out){
    int b = blockIdx.x, tid = threadIdx.x;
    float a0 = 0.f, a1 = 0.f;
    for (int j = tid; j < 1024; j += 256){
        float v = lk(y[b * 1024 + j]);
        a0 += v * fc2_w[j];
        a1 += v * fc2_w[1024 + j];
    }
    for (int off = 32; off; off >>= 1){
        a0 += __shfl_xor(a0, off, 64);
        a1 += __shfl_xor(a1, off, 64);
    }
    __shared__ float s0[4], s1[4];
    int wid = tid >> 6, lane = tid & 63;
    if (lane == 0){ s0[wid] = a0; s1[wid] = a1; }
    __syncthreads();
    if (tid == 0){
        float l0 = s0[0] + s0[1] + s0[2] + s0[3] + fc2_b[0];
        float l1 = s1[0] + s1[1] + s1[2] + s1[3] + fc2_b[1];
        float m = fmaxf(l0, l1);
        float lse = m + logf(expf(l0 - m) + expf(l1 - m));
        out[b * 2 + 0] = l0 - lse;
        out[b * 2 + 1] = l1 - lse;
    }
}

extern "C" void kernel_launch(void* const* d_in, const int* in_sizes, int n_in,
                              void* d_out, int out_size, void* d_ws, size_t ws_size,
                              hipStream_t stream){
    (void)in_sizes; (void)n_in; (void)out_size; (void)ws_size;
    const float* x     = (const float*)d_in[0];
    const float* W1    = (const float*)d_in[1];
    const float* b1    = (const float*)d_in[2];
    const float* W2    = (const float*)d_in[3];
    const float* b2    = (const float*)d_in[4];
    const float* fc1_w = (const float*)d_in[5];
    const float* fc1_b = (const float*)d_in[6];
    const float* fc2_w = (const float*)d_in[7];
    const float* fc2_b = (const float*)d_in[8];
    const int*   edges = (const int*)d_in[9];
    const int*   esrc  = edges;
    const int*   edst  = edges + NE;

    char* w = (char*)d_ws;
    u16* ha  = (u16*)w;           w += (size_t)NTOT * CDIM * 2;        // 16 MB
    u16* hb  = (u16*)w;           w += (size_t)NTOT * CDIM * 2;        // 16 MB
    u16* Wt  = (u16*)w;           w += (size_t)NLAYER * 2 * CDIM * CDIM * 2; // 256 KB
    float* y = (float*)w;         w += (size_t)NTOT * 4;               // 256 KB
    int* cnt = (int*)w;           w += (size_t)NTOT * 4;               // 256 KB
    u16* csrp = (u16*)w;          w += (size_t)(NTOT + 4) * PAD * 2;   // 8 MB (+4 rows: prefetch overshoot)

    hipMemsetAsync(cnt, 0, (size_t)NTOT * 4, stream);
    k_cast_x<<<4096, 256, 0, stream>>>(x, ha);
    k_conv_w<<<512, 256, 0, stream>>>(W1, W2, Wt);
    k_fillx <<<4096, 256, 0, stream>>>(esrc, edst, cnt, csrp);

    u16* hin = ha;
    u16* hout = hb;
    for (int l = 0; l < NLAYER; ++l){
        k_layer16<<<4096, 256, 0, stream>>>(hin, cnt, csrp, Wt, b1, b2, hout,
                                            fc1_w, fc1_b, y,
                                            l, (l < NLAYER - 1) ? 1 : 0,
                                            (l == NLAYER - 1) ? 1 : 0);
        u16* tmp = hin; hin = hout; hout = tmp;
    }
    k_fc2<<<NGRAPH, 256, 0, stream>>>(y, fc2_w, fc2_b, (float*)d_out);
}

// Round 13
// 306.477 us; speedup vs baseline: 1.1830x; 1.1830x over previous
//
#include <hip/hip_runtime.h>
#include <hip/hip_bf16.h>

#define NTOT   65536
#define CDIM   128
#define NE     1048576
#define NGRAPH 64
#define NNODE  1024
#define NLAYER 4
#define SLOPE  0.01f
#define PAD    64

typedef __attribute__((ext_vector_type(8))) short short8;   // 8 bf16 (4 VGPRs) MFMA frag
typedef __attribute__((ext_vector_type(4))) float f32x4;    // MFMA accum frag
typedef __attribute__((ext_vector_type(8))) unsigned short ushort8v;
typedef unsigned int u32;
typedef unsigned short u16;

__device__ __forceinline__ float bf2f_lo(u32 v){ return __uint_as_float(v << 16); }
__device__ __forceinline__ float bf2f_hi(u32 v){ return __uint_as_float(v & 0xffff0000u); }
__device__ __forceinline__ u16 f2bf(float f){
    u32 u = __float_as_uint(f);
    u += 0x7fffu + ((u >> 16) & 1u);      // round-to-nearest-even
    return (u16)(u >> 16);
}
__device__ __forceinline__ float lk(float x){ return x >= 0.f ? x : SLOPE * x; }

// predicated accumulate: 1 cndmask + 8 fmac. Garbage rows are always finite
// (any u16 index is in-bounds of h, rows always fully initialized), so 0*val = 0.
__device__ __forceinline__ void accm(float* a, uint4 w, bool pr){
    float f = pr ? 1.f : 0.f;
    a[0] = fmaf(f, bf2f_lo(w.x), a[0]); a[1] = fmaf(f, bf2f_hi(w.x), a[1]);
    a[2] = fmaf(f, bf2f_lo(w.y), a[2]); a[3] = fmaf(f, bf2f_hi(w.y), a[3]);
    a[4] = fmaf(f, bf2f_lo(w.z), a[4]); a[5] = fmaf(f, bf2f_hi(w.z), a[5]);
    a[6] = fmaf(f, bf2f_lo(w.w), a[6]); a[7] = fmaf(f, bf2f_hi(w.w), a[7]);
}

// ---------------- cast x (f32) -> h (bf16) ----------------
__global__ void k_cast_x(const float* __restrict__ x, u16* __restrict__ h){
    int i = blockIdx.x * 256 + threadIdx.x;          // 8 elems per thread
    const float4* x4 = (const float4*)x;
    float4 a = x4[i * 2], b = x4[i * 2 + 1];
    u32 r0 = (u32)f2bf(a.x) | ((u32)f2bf(a.y) << 16);
    u32 r1 = (u32)f2bf(a.z) | ((u32)f2bf(a.w) << 16);
    u32 r2 = (u32)f2bf(b.x) | ((u32)f2bf(b.y) << 16);
    u32 r3 = (u32)f2bf(b.z) | ((u32)f2bf(b.w) << 16);
    ((uint4*)h)[i] = make_uint4(r0, r1, r2, r3);
}

// ------- convert + transpose weights: Wt[l][g][c][k] = (bf16) W_g[l][k][c] -------
__global__ void k_conv_w(const float* __restrict__ W1, const float* __restrict__ W2,
                         u16* __restrict__ Wt){
    int idx = blockIdx.x * 256 + threadIdx.x;        // L*2*128*128 = 131072
    int k = idx & 127;
    int c = (idx >> 7) & 127;
    int g = (idx >> 14) & 1;
    int l = idx >> 15;
    const float* W = g ? W2 : W1;
    Wt[idx] = f2bf(W[(l * 128 + k) * 128 + c]);
}

// ------- XCD-partitioned padded-CSR fill -------
__global__ void k_fillx(const int* __restrict__ src, const int* __restrict__ dst,
                        int* __restrict__ cnt, u16* __restrict__ csrp){
    int part = blockIdx.x & 7;
    int g    = blockIdx.x >> 3;                       // 0..511
    int e0   = g * 2048 + threadIdx.x * 8;
    int4 d0 = *(const int4*)(dst + e0);
    int4 d1 = *(const int4*)(dst + e0 + 4);
    int4 s0 = *(const int4*)(src + e0);
    int4 s1 = *(const int4*)(src + e0 + 4);
    int d, s, p;
    #define DO_EDGE(dd, ss) d = (dd); s = (ss); \
        if ((d >> 13) == part){ p = atomicAdd(&cnt[d], 1); if (p < PAD) csrp[d * PAD + p] = (u16)s; }
    DO_EDGE(d0.x, s0.x); DO_EDGE(d0.y, s0.y); DO_EDGE(d0.z, s0.z); DO_EDGE(d0.w, s0.w);
    DO_EDGE(d1.x, s1.x); DO_EDGE(d1.y, s1.y); DO_EDGE(d1.z, s1.z); DO_EDGE(d1.w, s1.w);
    #undef DO_EDGE
}

// 8-row gather into named register set (static indices, rule #20)
#define LD8(P, I) \
    P##0 = h4[(size_t)(I)[0] * 16 + l16c]; \
    P##1 = h4[(size_t)(I)[1] * 16 + l16c]; \
    P##2 = h4[(size_t)(I)[2] * 16 + l16c]; \
    P##3 = h4[(size_t)(I)[3] * 16 + l16c]; \
    P##4 = h4[(size_t)(I)[4] * 16 + l16c]; \
    P##5 = h4[(size_t)(I)[5] * 16 + l16c]; \
    P##6 = h4[(size_t)(I)[6] * 16 + l16c]; \
    P##7 = h4[(size_t)(I)[7] * 16 + l16c];

#define ACC8P(P, base) \
    accm(a0, P##0, (base) + 0 < e); accm(a1, P##1, (base) + 1 < e); \
    accm(a0, P##2, (base) + 2 < e); accm(a1, P##3, (base) + 3 < e); \
    accm(a0, P##4, (base) + 4 < e); accm(a1, P##5, (base) + 5 < e); \
    accm(a0, P##6, (base) + 6 < e); accm(a1, P##7, (base) + 7 < e);

// ------- fused layer at GATHER geometry: 16 nodes/block, 4096 blocks -------
// Phase 0: gather with explicit 2-deep ROW-load pipeline (chunk c+1's rows in
//          flight while accumulating chunk c). Speculative chunks index-masked
//          to row 0 (hot in every L2) -> no garbage fabric traffic.
// Phase 1/2: 4 waves; wave w computes cols [w*32, w*32+32) of both GEMMs.
__global__ __launch_bounds__(256) void k_layer16(const u16* __restrict__ h,
                                                 const int* __restrict__ cnt,
                                                 const u16* __restrict__ csrp,
                                                 const u16* __restrict__ Wt,
                                                 const float* __restrict__ b1,
                                                 const float* __restrict__ b2,
                                                 u16* __restrict__ hout,
                                                 const float* __restrict__ fc1_w,
                                                 const float* __restrict__ fc1_b,
                                                 float* __restrict__ y,
                                                 int layer, int act, int fuse_fc1){
    __shared__ __align__(16) u16 t_lds[16][136];      // agg result (A for GEMM1)
    __shared__ __align__(16) u16 u_lds[16][136];      // GEMM1 out (A for GEMM2)
    __shared__ float fcp[4][16];                      // FC1 per-wave partials
    int tid = threadIdx.x;
    int nb  = blockIdx.x;

    // ---- phase 0: gather ----
    {
        int row  = tid >> 4;
        int l16c = tid & 15;
        int n = nb * 16 + row;
        const uint4* h4 = (const uint4*)h;
        int e = min(cnt[n], PAD);
        const u16* rowp = csrp + (size_t)n * PAD;
        int nch = (e + 7) >> 3;

        float a0[8], a1[8];
        uint4 v = h4[(size_t)n * 16 + l16c];
        a0[0] = bf2f_lo(v.x); a0[1] = bf2f_hi(v.x);
        a0[2] = bf2f_lo(v.y); a0[3] = bf2f_hi(v.y);
        a0[4] = bf2f_lo(v.z); a0[5] = bf2f_hi(v.z);
        a0[6] = bf2f_lo(v.w); a0[7] = bf2f_hi(v.w);
        for (int f = 0; f < 8; ++f) a1[f] = 0.f;

        uint4 A0, A1, A2, A3, A4, A5, A6, A7;
        uint4 B0, B1, B2, B3, B4, B5, B6, B7;
        ushort8v zer = (ushort8v)0;

        // prime: chunk 0 rows (masked to row 0 if no edges)
        ushort8v iA = *(const ushort8v*)(rowp);
        if (nch < 1) iA = zer;
        LD8(A, iA);
        ushort8v iB = *(const ushort8v*)(rowp + 8);

        int c = 0;
        while (c < nch){
            // issue chunk c+1 rows (masked if beyond last chunk), prefetch idx c+2
            ushort8v iu = (c + 1 < nch) ? iB : zer;
            LD8(B, iu);
            iA = *(const ushort8v*)(rowp + (size_t)(c + 2) * 8);
            ACC8P(A, c * 8);
            ++c;
            if (c >= nch) break;
            ushort8v iv = (c + 1 < nch) ? iA : zer;
            LD8(A, iv);
            iB = *(const ushort8v*)(rowp + (size_t)(c + 2) * 8);
            ACC8P(B, c * 8);
            ++c;
        }

        u32 r0 = (u32)f2bf(a0[0] + a1[0]) | ((u32)f2bf(a0[1] + a1[1]) << 16);
        u32 r1 = (u32)f2bf(a0[2] + a1[2]) | ((u32)f2bf(a0[3] + a1[3]) << 16);
        u32 r2 = (u32)f2bf(a0[4] + a1[4]) | ((u32)f2bf(a0[5] + a1[5]) << 16);
        u32 r3 = (u32)f2bf(a0[6] + a1[6]) | ((u32)f2bf(a0[7] + a1[7]) << 16);
        *(uint4*)(&t_lds[row][l16c * 8]) = make_uint4(r0, r1, r2, r3);
    }
    __syncthreads();

    int wid = tid >> 6, lane = tid & 63;
    int l16 = lane & 15, kg = lane >> 4;
    const u16* Wt1 = Wt + (size_t)(layer * 2) * 16384;
    const u16* Wt2 = Wt1 + 16384;

    // ---- GEMM1: U[:, wid*32 .. +32) = T @ W1 slice ----
    f32x4 acc[2];
    acc[0] = (f32x4){0.f, 0.f, 0.f, 0.f};
    acc[1] = (f32x4){0.f, 0.f, 0.f, 0.f};
    for (int ks = 0; ks < 4; ++ks){
        int k0 = ks * 32 + kg * 8;
        short8 afrag = *(const short8*)(&t_lds[l16][k0]);
        for (int f = 0; f < 2; ++f){
            short8 bfrag = *(const short8*)(Wt1 + (size_t)(wid * 32 + f * 16 + l16) * 128 + k0);
            acc[f] = __builtin_amdgcn_mfma_f32_16x16x32_bf16(afrag, bfrag, acc[f], 0, 0, 0);
        }
    }
    for (int f = 0; f < 2; ++f){
        int col = wid * 32 + f * 16 + l16;
        float bv = b1[layer * 128 + col];
        for (int j = 0; j < 4; ++j)
            u_lds[kg * 4 + j][col] = f2bf(lk(acc[f][j] + bv));
    }
    __syncthreads();

    // ---- GEMM2: H[:, wid*32 .. +32) = U @ W2 slice ----
    f32x4 acc2[2];
    acc2[0] = (f32x4){0.f, 0.f, 0.f, 0.f};
    acc2[1] = (f32x4){0.f, 0.f, 0.f, 0.f};
    for (int ks = 0; ks < 4; ++ks){
        int k0 = ks * 32 + kg * 8;
        short8 afrag = *(const short8*)(&u_lds[l16][k0]);
        for (int f = 0; f < 2; ++f){
            short8 bfrag = *(const short8*)(Wt2 + (size_t)(wid * 32 + f * 16 + l16) * 128 + k0);
            acc2[f] = __builtin_amdgcn_mfma_f32_16x16x32_bf16(afrag, bfrag, acc2[f], 0, 0, 0);
        }
    }

    if (fuse_fc1){
        float part[4] = {0.f, 0.f, 0.f, 0.f};
        for (int f = 0; f < 2; ++f){
            int col = wid * 32 + f * 16 + l16;
            float bv = b2[layer * 128 + col];
            float wv = fc1_w[col];
            for (int j = 0; j < 4; ++j)
                part[j] += lk(acc2[f][j] + bv) * wv;
        }
        for (int off = 8; off; off >>= 1)
            for (int j = 0; j < 4; ++j)
                part[j] += __shfl_xor(part[j], off, 64);
        if (l16 == 0)
            for (int j = 0; j < 4; ++j)
                fcp[wid][kg * 4 + j] = part[j];
        __syncthreads();
        if (tid < 16)
            y[nb * 16 + tid] = fcp[0][tid] + fcp[1][tid] + fcp[2][tid] + fcp[3][tid] + fc1_b[0];
    } else {
        for (int f = 0; f < 2; ++f){
            int col = wid * 32 + f * 16 + l16;
            float bv = b2[layer * 128 + col];
            for (int j = 0; j < 4; ++j){
                float v = acc2[f][j] + bv;
                if (act) v = lk(v);
                hout[(size_t)(nb * 16 + kg * 4 + j) * 128 + col] = f2bf(v);
            }
        }
    }
}

// ---------------- FC2 + log_softmax ----------------
__global__ void k_fc2(const float* __restrict__ y, const float* __restrict__ fc2_w,
                      const float* __restrict__ fc2_b, float* __restrict__ out){
    int b = blockIdx.x, tid = threadIdx.x;
    float a0 = 0.f, a1 = 0.f;
    for (int j = tid; j < 1024; j += 256){
        float v = lk(y[b * 1024 + j]);
        a0 += v * fc2_w[j];
        a1 += v * fc2_w[1024 + j];
    }
    for (int off = 32; off; off >>= 1){
        a0 += __shfl_xor(a0, off, 64);
        a1 += __shfl_xor(a1, off, 64);
    }
    __shared__ float s0[4], s1[4];
    int wid = tid >> 6, lane = tid & 63;
    if (lane == 0){ s0[wid] = a0; s1[wid] = a1; }
    __syncthreads();
    if (tid == 0){
        float l0 = s0[0] + s0[1] + s0[2] + s0[3] + fc2_b[0];
        float l1 = s1[0] + s1[1] + s1[2] + s1[3] + fc2_b[1];
        float m = fmaxf(l0, l1);
        float lse = m + logf(expf(l0 - m) + expf(l1 - m));
        out[b * 2 + 0] = l0 - lse;
        out[b * 2 + 1] = l1 - lse;
    }
}

extern "C" void kernel_launch(void* const* d_in, const int* in_sizes, int n_in,
                              void* d_out, int out_size, void* d_ws, size_t ws_size,
                              hipStream_t stream){
    (void)in_sizes; (void)n_in; (void)out_size; (void)ws_size;
    const float* x     = (const float*)d_in[0];
    const float* W1    = (const float*)d_in[1];
    const float* b1    = (const float*)d_in[2];
    const float* W2    = (const float*)d_in[3];
    const float* b2    = (const float*)d_in[4];
    const float* fc1_w = (const float*)d_in[5];
    const float* fc1_b = (const float*)d_in[6];
    const float* fc2_w = (const float*)d_in[7];
    const float* fc2_b = (const float*)d_in[8];
    const int*   edges = (const int*)d_in[9];
    const int*   esrc  = edges;
    const int*   edst  = edges + NE;

    char* w = (char*)d_ws;
    u16* ha  = (u16*)w;           w += (size_t)NTOT * CDIM * 2;        // 16 MB
    u16* hb  = (u16*)w;           w += (size_t)NTOT * CDIM * 2;        // 16 MB
    u16* Wt  = (u16*)w;           w += (size_t)NLAYER * 2 * CDIM * CDIM * 2; // 256 KB
    float* y = (float*)w;         w += (size_t)NTOT * 4;               // 256 KB
    int* cnt = (int*)w;           w += (size_t)NTOT * 4;               // 256 KB
    u16* csrp = (u16*)w;          w += (size_t)(NTOT + 2) * PAD * 2;   // 8 MB (+2 rows: prefetch overshoot)

    hipMemsetAsync(cnt, 0, (size_t)NTOT * 4, stream);
    k_cast_x<<<4096, 256, 0, stream>>>(x, ha);
    k_conv_w<<<512, 256, 0, stream>>>(W1, W2, Wt);
    k_fillx <<<4096, 256, 0, stream>>>(esrc, edst, cnt, csrp);

    u16* hin = ha;
    u16* hout = hb;
    for (int l = 0; l < NLAYER; ++l){
        k_layer16<<<4096, 256, 0, stream>>>(hin, cnt, csrp, Wt, b1, b2, hout,
                                            fc1_w, fc1_b, y,
                                            l, (l < NLAYER - 1) ? 1 : 0,
                                            (l == NLAYER - 1) ? 1 : 0);
        u16* tmp = hin; hin = hout; hout = tmp;
    }
    k_fc2<<<NGRAPH, 256, 0, stream>>>(y, fc2_w, fc2_b, (float*)d_out);
}